// Round 1
// baseline (313.109 us; speedup 1.0000x reference)
//
#include <hip/hip_runtime.h>

typedef float f2 __attribute__((ext_vector_type(2)));
typedef _Float16 h2 __attribute__((ext_vector_type(2)));
typedef _Float16 h8 __attribute__((ext_vector_type(8)));

#define IMG 512
#define TW 32
#define TH 32
#define NG 12            // float4 col-groups per tile row: 48 cols = 32 out + 8 halo each side
#define SROW 148         // LDS row stride in dwords: 96 A(f2 fp32) + 48 B(half2) + 4 pad
                         //   -> 592 B/row; quad count 37 (ODD: full bank-quad permutation over rows)
#define BOFFD 96         // B-part offset within a row, in dwords (384 B, 16B-aligned)
#define N_TOT (16 * 3 * 512 * 512)
#define NBLK (256 * 48)  // total blocks of ssim_main
#define NSLOT 1024       // fallback atomic slots

// Gaussian(win=11, sigma=1.5), normalized, pre-doubled (SGPR-pair broadcast for pk ops).
__device__ __constant__ f2 Gw2[11] = {
    {0.00102838f, 0.00102838f}, {0.00759876f, 0.00759876f},
    {0.03600077f, 0.03600077f}, {0.10936086f, 0.10936086f},
    {0.21300537f, 0.21300537f}, {0.26601173f, 0.26601173f},
    {0.21300537f, 0.21300537f}, {0.10936086f, 0.10936086f},
    {0.03600077f, 0.03600077f}, {0.00759876f, 0.00759876f},
    {0.00102838f, 0.00102838f}};

// Same weights in fp16 pairs for the packed-fp16 B blur.
__device__ __constant__ h2 Gh2[11] = {
    {(_Float16)0.00102838f, (_Float16)0.00102838f},
    {(_Float16)0.00759876f, (_Float16)0.00759876f},
    {(_Float16)0.03600077f, (_Float16)0.03600077f},
    {(_Float16)0.10936086f, (_Float16)0.10936086f},
    {(_Float16)0.21300537f, (_Float16)0.21300537f},
    {(_Float16)0.26601173f, (_Float16)0.26601173f},
    {(_Float16)0.21300537f, (_Float16)0.21300537f},
    {(_Float16)0.10936086f, (_Float16)0.10936086f},
    {(_Float16)0.03600077f, (_Float16)0.03600077f},
    {(_Float16)0.00759876f, (_Float16)0.00759876f},
    {(_Float16)0.00102838f, (_Float16)0.00102838f}};

// Pack two f32 -> half2 (v_cvt_pkrtz_f16_f32). RTZ bias ~ulp/2 -> final-scalar
// bias ~1.4e-3, well under the 1.98e-2 absmax threshold.
__device__ __forceinline__ h2 pkrtz(float a, float b) {
    auto t = __builtin_amdgcn_cvt_pkrtz(a, b);
    h2 r;
    __builtin_memcpy(&r, &t, sizeof(r));
    return r;
}

// Packed vertical taps for a row-pair from one input row k.
__device__ __forceinline__ void vtaps(const float4 P, const float4 T, const int k,
                                      f2 A0[4][2], f2 A1[4][2]) {
    const f2 p[2] = {{P.x, P.y}, {P.z, P.w}};
    const f2 t[2] = {{T.x, T.y}, {T.z, T.w}};
#pragma unroll
    for (int h = 0; h < 2; ++h) {
        const f2 ss = p[h] * p[h] + t[h] * t[h];
        const f2 pt = p[h] * t[h];
        if (k < 11) {                              // tap k for row r0
            const f2 w = Gw2[k];
            A0[0][h] += w * p[h];
            A0[1][h] += w * t[h];
            A0[2][h] += w * ss;
            A0[3][h] += w * pt;
        }
        if (k > 0) {                               // tap k-1 for row r0+1
            const f2 w = Gw2[k - 1];
            A1[0][h] += w * p[h];
            A1[1][h] += w * t[h];
            A1[2][h] += w * ss;
            A1[3][h] += w * pt;
        }
    }
}

// PINNED at (256,8): measured three times VGPR=60/no-spill; (256,5) and (256,6)
// both triggered pathological spill (WRITE_SIZE 89-112 MB, VGPR 40-48). Do not touch.
// Also: never hand-pipeline the k-loop (round-8 spill); plain loads, compiler schedules.
__global__ __launch_bounds__(256, 8) void ssim_main(const float* __restrict__ pred,
                                                    const float* __restrict__ tgt,
                                                    float* __restrict__ ws,
                                                    int parts_mode) {
    // Unified vertically-blurred plane, 32 rows x (48 A-cols fp32 | 48 B-cols fp16).
    //   A(row,c) = (vblur p, vblur t)          f2   at dword row*SROW + 2c
    //   B(row,c) = half2(vblur p^2+t^2, p*t)   h2   at dword row*SROW + BOFFD + c
    // 32*148*4 = 18944 B -> <=20 KiB alloc -> 8 blocks/CU (vs 6 at the old fp32 plane).
    __shared__ __align__(16) float plane[TH * SROW];
    __shared__ float red[4];

    const int tid = threadIdx.x;
    const int tile = blockIdx.x;             // 16x16 tiles of 32x32
    const int plane_id = blockIdx.y;         // 48 planes
    const int tile_x = tile & 15;
    const int tile_y = tile >> 4;
    const int tx = tile_x * TW;
    const int ty = tile_y * TH;
    const float* pbase = pred + (size_t)plane_id * (IMG * IMG);
    const float* tbase = tgt + (size_t)plane_id * (IMG * IMG);

    // ---- Phase 1: vertical 11-tap blur straight from global, row-pair per task ----
    if (tid < NG * 16) {
        const int g4 = tid % NG;             // col group
        const int rp = tid / NG;             // row pair
        const int r0 = rp * 2;               // local output row
        const int col = tx - 8 + (g4 << 2);  // global col of float4 (16B-aligned)
        const int ybase = ty + r0 - 5;

        f2 A0[4][2], A1[4][2];
#pragma unroll
        for (int q = 0; q < 4; ++q)
#pragma unroll
            for (int h = 0; h < 2; ++h) { A0[q][h] = (f2)0.f; A1[q][h] = (f2)0.f; }

        // Block-uniform branch (scalar, no divergence); loads plain, compiler-scheduled.
        if ((unsigned)(tile_x - 1) < 14u && (unsigned)(tile_y - 1) < 14u) {
            const float* pp = pbase + (ybase * IMG + col);
            const float* tp = tbase + (ybase * IMG + col);
#pragma unroll
            for (int k = 0; k < 12; ++k) {
                const float4 P = *(const float4*)(pp + k * IMG);
                const float4 T = *(const float4*)(tp + k * IMG);
                vtaps(P, T, k, A0, A1);
            }
        } else {
            const bool xin = (unsigned)col < (unsigned)IMG;  // all-in or all-out
#pragma unroll
            for (int k = 0; k < 12; ++k) {
                const int y = ybase + k;
                float4 P = make_float4(0.f, 0.f, 0.f, 0.f);
                float4 T = make_float4(0.f, 0.f, 0.f, 0.f);
                if (xin && (unsigned)y < (unsigned)IMG) {
                    const int gidx = y * IMG + col;
                    P = *(const float4*)(pbase + gidx);
                    T = *(const float4*)(tbase + gidx);
                }
                vtaps(P, T, k, A0, A1);
            }
        }

        // Transpose in registers -> b128 stores. Row order parity-swapped per rp so each
        // wave's store instruction mixes even/odd bank-quad row offsets (5*r mod 8).
        const int cb = g4 << 2;              // pixel col base (col 0 == global tx-8)
#pragma unroll
        for (int rr = 0; rr < 2; ++rr) {
            const int r = rr ^ (rp & 1);
            f2 (*A)[2] = r ? A1 : A0;
            float* rowA = &plane[(r0 + r) * SROW + (cb << 1)];
            *(float4*)rowA       = make_float4(A[0][0].x, A[1][0].x, A[0][0].y, A[1][0].y);
            *(float4*)(rowA + 4) = make_float4(A[0][1].x, A[1][1].x, A[0][1].y, A[1][1].y);
            // B: half2(ss, pt) per pixel; 4 pixels = 16 B = one ds_write_b128.
            const h2 b0 = pkrtz(A[2][0].x, A[3][0].x);
            const h2 b1 = pkrtz(A[2][0].y, A[3][0].y);
            const h2 b2 = pkrtz(A[2][1].x, A[3][1].x);
            const h2 b3 = pkrtz(A[2][1].y, A[3][1].y);
            const h8 bv = (h8){b0[0], b0[1], b1[0], b1[1], b2[0], b2[1], b3[0], b3[1]};
            *(h8*)&plane[(r0 + r) * SROW + BOFFD + cb] = bv;
        }
    }
    __syncthreads();

    // ---- Phase 2: packed horizontal 11-tap blur + SSIM map, 4 outputs per thread ----
    float lsum = 0.f;
    {
        const int oy = tid >> 3;             // 32 rows
        const int ox = (tid & 7) << 2;       // 8 groups of 4 output cols
        const float* rowbase = &plane[oy * SROW];

        // A part (fp32 pk): output local col X needs plane cols X+3..X+13;
        // union j=0..3: ox+3..ox+16. Load f2 cols ox+2..ox+17 (8 x b128, 16B-aligned).
        f2 acc[4];                           // (mu1, mu2) per j
#pragma unroll
        for (int j = 0; j < 4; ++j) acc[j] = (f2)0.f;
        {
            const float4* rowA = (const float4*)(rowbase + ((ox + 2) << 1));
            f2 w[16];
#pragma unroll
            for (int i = 0; i < 8; ++i) {
                const float4 q = rowA[i];
                w[2 * i] = (f2){q.x, q.y};
                w[2 * i + 1] = (f2){q.z, q.w};
            }
#pragma unroll
            for (int k = 0; k < 11; ++k) {
                const f2 g = Gw2[k];
#pragma unroll
                for (int j = 0; j < 4; ++j) acc[j] += g * w[1 + j + k];
            }
        }

        // B part (fp16 pk): need pixels ox+3..ox+16; load pixels ox..ox+19
        // (5 x b128, 16B-aligned; contiguous 32-dword span per row -> conflict-free).
        h2 sacc[4];                          // half2(bss, bpt) per j
#pragma unroll
        for (int j = 0; j < 4; ++j) sacc[j] = (h2){(_Float16)0.f, (_Float16)0.f};
        {
            const h8* rowB = (const h8*)(rowbase + BOFFD + ox);
            h2 wb[20];
#pragma unroll
            for (int i = 0; i < 5; ++i) {
                const h8 q = rowB[i];
                wb[4 * i]     = (h2){q[0], q[1]};
                wb[4 * i + 1] = (h2){q[2], q[3]};
                wb[4 * i + 2] = (h2){q[4], q[5]};
                wb[4 * i + 3] = (h2){q[6], q[7]};
            }
#pragma unroll
            for (int k = 0; k < 11; ++k) {
                const h2 g = Gh2[k];
#pragma unroll
                for (int j = 0; j < 4; ++j) sacc[j] += g * wb[3 + j + k];
            }
        }

        const float C1 = 0.0001f;            // 0.01^2
        const float C2 = 0.0009f;            // 0.03^2
#pragma unroll
        for (int j = 0; j < 4; ++j) {
            const float m1 = acc[j].x, m2 = acc[j].y;
            const float bss = (float)sacc[j][0], bpt = (float)sacc[j][1];
            const float mu1s = m1 * m1;
            const float mu2s = m2 * m2;
            const float mu12 = m1 * m2;
            const float A = mu1s + mu2s;
            const float s12 = bpt - mu12;    // sigma12
            const float sden = bss - A;      // sigma1^2 + sigma2^2
            const float num = fmaf(2.f, mu12, C1) * fmaf(2.f, s12, C2);
            const float den = (A + C1) * (sden + C2);
            lsum += num * __builtin_amdgcn_rcpf(den);   // rcp err ~1e-7 << 1.98e-2 threshold
        }
    }

    // ---- Reduction: wave shuffle -> LDS -> one plain store per block ----
#pragma unroll
    for (int off = 32; off > 0; off >>= 1) lsum += __shfl_down(lsum, off, 64);
    if ((tid & 63) == 0) red[tid >> 6] = lsum;
    __syncthreads();
    if (tid == 0) {
        const float bs = (red[0] + red[1]) + (red[2] + red[3]);
        const int bid = blockIdx.y * gridDim.x + blockIdx.x;
        if (parts_mode) {
            ws[bid] = bs;                    // contention-free
        } else {
            atomicAdd(&ws[bid & (NSLOT - 1)], bs);  // fallback: shallow contention
        }
    }
}

// Sum `count4` float4 partials from ws, write 1 - sum/N.
__global__ __launch_bounds__(1024) void ssim_final(const float4* __restrict__ ws4,
                                                   float* __restrict__ out, int count4) {
    __shared__ float red[16];
    const int tid = threadIdx.x;
    float s = 0.f;
    for (int i = tid; i < count4; i += 1024) {
        const float4 w = ws4[i];
        s += (w.x + w.y) + (w.z + w.w);
    }
#pragma unroll
    for (int off = 32; off > 0; off >>= 1) s += __shfl_down(s, off, 64);
    if ((tid & 63) == 0) red[tid >> 6] = s;
    __syncthreads();
    if (tid == 0) {
        float tot = 0.f;
#pragma unroll
        for (int i = 0; i < 16; ++i) tot += red[i];
        out[0] = 1.0f - tot * (1.0f / (float)N_TOT);
    }
}

extern "C" void kernel_launch(void* const* d_in, const int* in_sizes, int n_in,
                              void* d_out, int out_size, void* d_ws, size_t ws_size,
                              hipStream_t stream) {
    const float* pred = (const float*)d_in[0];
    const float* tgt = (const float*)d_in[1];
    float* out = (float*)d_out;
    float* ws = (float*)d_ws;

    const int parts_mode = (ws_size >= (size_t)NBLK * sizeof(float)) ? 1 : 0;
    if (!parts_mode) {
        hipMemsetAsync(ws, 0, NSLOT * sizeof(float), stream);
    }
    dim3 grid(256, 48);  // 16x16 tiles x (16*3) planes
    ssim_main<<<grid, 256, 0, stream>>>(pred, tgt, ws, parts_mode);
    ssim_final<<<1, 1024, 0, stream>>>((const float4*)ws, out,
                                       (parts_mode ? NBLK : NSLOT) / 4);
}

// Round 2
// 300.837 us; speedup vs baseline: 1.0408x; 1.0408x over previous
//
#include <hip/hip_runtime.h>

typedef float f2 __attribute__((ext_vector_type(2)));

#define IMG 512
#define TW 32
#define TH 32
#define NG 12            // float4 col-groups per tile row: 48 cols = 32 out + 8 halo each side
#define SROW 148         // LDS row stride in dwords: 96 A(f2 fp32) + 48 B(packed half2) + 4 pad
                         //   -> 592 B/row; quad count 37 (ODD: full bank-quad permutation over rows)
#define BOFFD 96         // B-part offset within a row, in dwords (384 B, 16B-aligned)
#define N_TOT (16 * 3 * 512 * 512)
#define NBLK (256 * 48)  // total blocks of ssim_main
#define NSLOT 1024       // fallback atomic slots

// Gaussian(win=11, sigma=1.5), normalized, pre-doubled (SGPR-pair broadcast for pk ops).
__device__ __constant__ f2 Gw2[11] = {
    {0.00102838f, 0.00102838f}, {0.00759876f, 0.00759876f},
    {0.03600077f, 0.03600077f}, {0.10936086f, 0.10936086f},
    {0.21300537f, 0.21300537f}, {0.26601173f, 0.26601173f},
    {0.21300537f, 0.21300537f}, {0.10936086f, 0.10936086f},
    {0.03600077f, 0.03600077f}, {0.00759876f, 0.00759876f},
    {0.00102838f, 0.00102838f}};

// Pack two f32 -> u32 of 2xfp16 (v_cvt_pkrtz_f16_f32). Storage-only compression:
// RTZ bias ~ulp/2 on (bss~0.67, bpt~0.25) -> final-scalar bias ~2e-3 << 1.98e-2 threshold
// (round-1 harness-verified: passed with fp16 B plane).
__device__ __forceinline__ unsigned pkh(float a, float b) {
    auto t = __builtin_amdgcn_cvt_pkrtz(a, b);   // v2f16
    unsigned r;
    __builtin_memcpy(&r, &t, 4);
    return r;
}

// Unpack u32 of 2xfp16 -> f2 (two v_cvt_f32_f16).
__device__ __forceinline__ f2 uph(unsigned u) {
    _Float16 h[2];
    __builtin_memcpy(h, &u, 4);
    return (f2){(float)h[0], (float)h[1]};
}

// Packed vertical taps for a row-pair from one input row k.
__device__ __forceinline__ void vtaps(const float4 P, const float4 T, const int k,
                                      f2 A0[4][2], f2 A1[4][2]) {
    const f2 p[2] = {{P.x, P.y}, {P.z, P.w}};
    const f2 t[2] = {{T.x, T.y}, {T.z, T.w}};
#pragma unroll
    for (int h = 0; h < 2; ++h) {
        const f2 ss = p[h] * p[h] + t[h] * t[h];
        const f2 pt = p[h] * t[h];
        if (k < 11) {                              // tap k for row r0
            const f2 w = Gw2[k];
            A0[0][h] += w * p[h];
            A0[1][h] += w * t[h];
            A0[2][h] += w * ss;
            A0[3][h] += w * pt;
        }
        if (k > 0) {                               // tap k-1 for row r0+1
            const f2 w = Gw2[k - 1];
            A1[0][h] += w * p[h];
            A1[1][h] += w * t[h];
            A1[2][h] += w * ss;
            A1[3][h] += w * pt;
        }
    }
}

// PINNED at (256,8): measured VGPR=60/no-spill on the fp32 version; deviations spill.
// NEVER runtime-index A0/A1 (round-1 post-mortem: `r ? A1 : A0` with runtime r put both
// accumulator arrays in scratch -> WRITE_SIZE 215 MB, 2x regression). Static unroll only.
__global__ __launch_bounds__(256, 8) void ssim_main(const float* __restrict__ pred,
                                                    const float* __restrict__ tgt,
                                                    float* __restrict__ ws,
                                                    int parts_mode) {
    // Unified vertically-blurred plane, 32 rows x (48 A-cols fp32 | 48 B-cols packed half2).
    //   A(row,c) = (vblur p, vblur t)              f2  at dword row*SROW + 2c
    //   B(row,c) = pkrtz(vblur p^2+t^2, vblur p*t) u32 at dword row*SROW + BOFFD + c
    // 32*148*4 = 18944 B -> 19456 alloc -> 8 blocks/CU (was 6 with the all-fp32 plane;
    // round-1 measured OccupancyPercent 61-63 at this footprint).
    __shared__ __align__(16) float plane[TH * SROW];
    __shared__ float red[4];

    const int tid = threadIdx.x;
    const int tile = blockIdx.x;             // 16x16 tiles of 32x32
    const int plane_id = blockIdx.y;         // 48 planes
    const int tile_x = tile & 15;
    const int tile_y = tile >> 4;
    const int tx = tile_x * TW;
    const int ty = tile_y * TH;
    const float* pbase = pred + (size_t)plane_id * (IMG * IMG);
    const float* tbase = tgt + (size_t)plane_id * (IMG * IMG);

    // ---- Phase 1: vertical 11-tap blur straight from global, row-pair per task ----
    if (tid < NG * 16) {
        const int g4 = tid % NG;             // col group
        const int rp = tid / NG;             // row pair
        const int r0 = rp * 2;               // local output row
        const int col = tx - 8 + (g4 << 2);  // global col of float4 (16B-aligned)
        const int ybase = ty + r0 - 5;

        f2 A0[4][2], A1[4][2];
#pragma unroll
        for (int q = 0; q < 4; ++q)
#pragma unroll
            for (int h = 0; h < 2; ++h) { A0[q][h] = (f2)0.f; A1[q][h] = (f2)0.f; }

        // Block-uniform branch (scalar, no divergence); loads plain, compiler-scheduled.
        if ((unsigned)(tile_x - 1) < 14u && (unsigned)(tile_y - 1) < 14u) {
            const float* pp = pbase + (ybase * IMG + col);
            const float* tp = tbase + (ybase * IMG + col);
#pragma unroll
            for (int k = 0; k < 12; ++k) {
                const float4 P = *(const float4*)(pp + k * IMG);
                const float4 T = *(const float4*)(tp + k * IMG);
                vtaps(P, T, k, A0, A1);
            }
        } else {
            const bool xin = (unsigned)col < (unsigned)IMG;  // all-in or all-out
#pragma unroll
            for (int k = 0; k < 12; ++k) {
                const int y = ybase + k;
                float4 P = make_float4(0.f, 0.f, 0.f, 0.f);
                float4 T = make_float4(0.f, 0.f, 0.f, 0.f);
                if (xin && (unsigned)y < (unsigned)IMG) {
                    const int gidx = y * IMG + col;
                    P = *(const float4*)(pbase + gidx);
                    T = *(const float4*)(tbase + gidx);
                }
                vtaps(P, T, k, A0, A1);
            }
        }

        // Transpose in registers -> b128 stores. r is a compile-time unroll var (see pin).
        const int cb = g4 << 2;              // pixel col base (col 0 == global tx-8)
#pragma unroll
        for (int r = 0; r < 2; ++r) {
            f2 (*A)[2] = r ? A1 : A0;
            float* rowA = &plane[(r0 + r) * SROW + (cb << 1)];
            *(float4*)rowA       = make_float4(A[0][0].x, A[1][0].x, A[0][0].y, A[1][0].y);
            *(float4*)(rowA + 4) = make_float4(A[0][1].x, A[1][1].x, A[0][1].y, A[1][1].y);
            // B: 4 pixels packed half2(ss,pt) = one uint4 = one ds_write_b128.
            uint4 bv;
            bv.x = pkh(A[2][0].x, A[3][0].x);
            bv.y = pkh(A[2][0].y, A[3][0].y);
            bv.z = pkh(A[2][1].x, A[3][1].x);
            bv.w = pkh(A[2][1].y, A[3][1].y);
            *(uint4*)&plane[(r0 + r) * SROW + BOFFD + cb] = bv;
        }
    }
    __syncthreads();

    // ---- Phase 2: packed horizontal 11-tap blur + SSIM map, 4 outputs per thread ----
    float lsum = 0.f;
    {
        const int oy = tid >> 3;             // 32 rows
        const int ox = (tid & 7) << 2;       // 8 groups of 4 output cols
        const float* rowbase = &plane[oy * SROW];

        // A part (fp32 pk): output local col X needs plane cols X+3..X+13;
        // union j=0..3: ox+3..ox+16. Load f2 cols ox+2..ox+17 (8 x b128, 16B-aligned).
        f2 acc[4];                           // (mu1, mu2) per j
#pragma unroll
        for (int j = 0; j < 4; ++j) acc[j] = (f2)0.f;
        {
            const float4* rowA = (const float4*)(rowbase + ((ox + 2) << 1));
            f2 w[16];
#pragma unroll
            for (int i = 0; i < 8; ++i) {
                const float4 q = rowA[i];
                w[2 * i] = (f2){q.x, q.y};
                w[2 * i + 1] = (f2){q.z, q.w};
            }
#pragma unroll
            for (int k = 0; k < 11; ++k) {
                const f2 g = Gw2[k];
#pragma unroll
                for (int j = 0; j < 4; ++j) acc[j] += g * w[1 + j + k];
            }
        }

        // B part: load packed pixels ox..ox+19 (5 x b128, contiguous span -> conflict-free),
        // unpack the needed 14 (ox+3..ox+16) to fp32, then the same packed fp32 tap loop.
        f2 sacc[4];                          // (bss, bpt) per j
#pragma unroll
        for (int j = 0; j < 4; ++j) sacc[j] = (f2)0.f;
        {
            const uint4* rowB = (const uint4*)(rowbase + BOFFD + ox);
            unsigned bp[20];
#pragma unroll
            for (int i = 0; i < 5; ++i) {
                const uint4 q = rowB[i];
                bp[4 * i] = q.x; bp[4 * i + 1] = q.y;
                bp[4 * i + 2] = q.z; bp[4 * i + 3] = q.w;
            }
            f2 w2[14];                       // pixel ox+3+m
#pragma unroll
            for (int m = 0; m < 14; ++m) w2[m] = uph(bp[m + 3]);
#pragma unroll
            for (int k = 0; k < 11; ++k) {
                const f2 g = Gw2[k];
#pragma unroll
                for (int j = 0; j < 4; ++j) sacc[j] += g * w2[j + k];
            }
        }

        const float C1 = 0.0001f;            // 0.01^2
        const float C2 = 0.0009f;            // 0.03^2
#pragma unroll
        for (int j = 0; j < 4; ++j) {
            const float m1 = acc[j].x, m2 = acc[j].y;
            const float bss = sacc[j].x, bpt = sacc[j].y;
            const float mu1s = m1 * m1;
            const float mu2s = m2 * m2;
            const float mu12 = m1 * m2;
            const float A = mu1s + mu2s;
            const float s12 = bpt - mu12;    // sigma12
            const float sden = bss - A;      // sigma1^2 + sigma2^2
            const float num = fmaf(2.f, mu12, C1) * fmaf(2.f, s12, C2);
            const float den = (A + C1) * (sden + C2);
            lsum += num * __builtin_amdgcn_rcpf(den);   // rcp err ~1e-7 << 1.98e-2 threshold
        }
    }

    // ---- Reduction: wave shuffle -> LDS -> one plain store per block ----
#pragma unroll
    for (int off = 32; off > 0; off >>= 1) lsum += __shfl_down(lsum, off, 64);
    if ((tid & 63) == 0) red[tid >> 6] = lsum;
    __syncthreads();
    if (tid == 0) {
        const float bs = (red[0] + red[1]) + (red[2] + red[3]);
        const int bid = blockIdx.y * gridDim.x + blockIdx.x;
        if (parts_mode) {
            ws[bid] = bs;                    // contention-free
        } else {
            atomicAdd(&ws[bid & (NSLOT - 1)], bs);  // fallback: shallow contention
        }
    }
}

// Sum `count4` float4 partials from ws, write 1 - sum/N.
__global__ __launch_bounds__(1024) void ssim_final(const float4* __restrict__ ws4,
                                                   float* __restrict__ out, int count4) {
    __shared__ float red[16];
    const int tid = threadIdx.x;
    float s = 0.f;
    for (int i = tid; i < count4; i += 1024) {
        const float4 w = ws4[i];
        s += (w.x + w.y) + (w.z + w.w);
    }
#pragma unroll
    for (int off = 32; off > 0; off >>= 1) s += __shfl_down(s, off, 64);
    if ((tid & 63) == 0) red[tid >> 6] = s;
    __syncthreads();
    if (tid == 0) {
        float tot = 0.f;
#pragma unroll
        for (int i = 0; i < 16; ++i) tot += red[i];
        out[0] = 1.0f - tot * (1.0f / (float)N_TOT);
    }
}

extern "C" void kernel_launch(void* const* d_in, const int* in_sizes, int n_in,
                              void* d_out, int out_size, void* d_ws, size_t ws_size,
                              hipStream_t stream) {
    const float* pred = (const float*)d_in[0];
    const float* tgt = (const float*)d_in[1];
    float* out = (float*)d_out;
    float* ws = (float*)d_ws;

    const int parts_mode = (ws_size >= (size_t)NBLK * sizeof(float)) ? 1 : 0;
    if (!parts_mode) {
        hipMemsetAsync(ws, 0, NSLOT * sizeof(float), stream);
    }
    dim3 grid(256, 48);  // 16x16 tiles x (16*3) planes
    ssim_main<<<grid, 256, 0, stream>>>(pred, tgt, ws, parts_mode);
    ssim_final<<<1, 1024, 0, stream>>>((const float4*)ws, out,
                                       (parts_mode ? NBLK : NSLOT) / 4);
}

// Round 3
// 296.842 us; speedup vs baseline: 1.0548x; 1.0135x over previous
//
#include <hip/hip_runtime.h>

typedef float f2 __attribute__((ext_vector_type(2)));

#define IMG 512
#define TW 32
#define TH 32
#define NG 12            // float4 col-groups per tile row: 48 cols = 32 out + 8 halo each side
#define SROW 148         // LDS row stride in dwords: 96 A(f2 fp32) + 48 B(packed half2) + 4 pad
                         //   -> 592 B/row; quad count 37 (ODD: full bank-quad permutation over rows)
#define BOFFD 96         // B-part offset within a row, in dwords (384 B, 16B-aligned)
#define N_TOT (16 * 3 * 512 * 512)
#define NBLK (256 * 48)  // total blocks of ssim_main
#define NSLOT 1024       // fallback atomic slots

// Gaussian(win=11, sigma=1.5), normalized, pre-doubled (SGPR-pair broadcast for pk ops).
__device__ __constant__ f2 Gw2[11] = {
    {0.00102838f, 0.00102838f}, {0.00759876f, 0.00759876f},
    {0.03600077f, 0.03600077f}, {0.10936086f, 0.10936086f},
    {0.21300537f, 0.21300537f}, {0.26601173f, 0.26601173f},
    {0.21300537f, 0.21300537f}, {0.10936086f, 0.10936086f},
    {0.03600077f, 0.03600077f}, {0.00759876f, 0.00759876f},
    {0.00102838f, 0.00102838f}};

// Pack two f32 -> u32 of 2xfp16 (v_cvt_pkrtz_f16_f32). Storage-only compression:
// rounds 1-2 harness-verified absmax 0.0 with fp16 B plane.
__device__ __forceinline__ unsigned pkh(float a, float b) {
    auto t = __builtin_amdgcn_cvt_pkrtz(a, b);   // v2f16
    unsigned r;
    __builtin_memcpy(&r, &t, 4);
    return r;
}

// Unpack u32 of 2xfp16 -> f2 (two v_cvt_f32_f16).
__device__ __forceinline__ f2 uph(unsigned u) {
    _Float16 h[2];
    __builtin_memcpy(h, &u, 4);
    return (f2){(float)h[0], (float)h[1]};
}

// Packed vertical taps for a row-pair from one input row k.
__device__ __forceinline__ void vtaps(const float4 P, const float4 T, const int k,
                                      f2 A0[4][2], f2 A1[4][2]) {
    const f2 p[2] = {{P.x, P.y}, {P.z, P.w}};
    const f2 t[2] = {{T.x, T.y}, {T.z, T.w}};
#pragma unroll
    for (int h = 0; h < 2; ++h) {
        const f2 ss = p[h] * p[h] + t[h] * t[h];
        const f2 pt = p[h] * t[h];
        if (k < 11) {                              // tap k for row r0
            const f2 w = Gw2[k];
            A0[0][h] += w * p[h];
            A0[1][h] += w * t[h];
            A0[2][h] += w * ss;
            A0[3][h] += w * pt;
        }
        if (k > 0) {                               // tap k-1 for row r0+1
            const f2 w = Gw2[k - 1];
            A1[0][h] += w * p[h];
            A1[1][h] += w * t[h];
            A1[2][h] += w * ss;
            A1[3][h] += w * pt;
        }
    }
}

// PINNED at (256,8): VGPR cap = 512/8 = 64. Round-2 post-mortem: phase-2 GATHER
// (bp[20]+w2[14]+acc live ~64+ dwords) blew this cap -> degenerate spill
// (VGPR 32, WRITE_SIZE 212 MB). Phase 2 must stay SCATTER-form (peak ~24 dwords).
// NEVER runtime-index register arrays. NEVER hand-pipeline the phase-1 k-loop.
__global__ __launch_bounds__(256, 8) void ssim_main(const float* __restrict__ pred,
                                                    const float* __restrict__ tgt,
                                                    float* __restrict__ ws,
                                                    int parts_mode) {
    // Unified vertically-blurred plane, 32 rows x (48 A-cols fp32 | 48 B-cols packed half2).
    //   A(row,c) = (vblur p, vblur t)              f2  at dword row*SROW + 2c
    //   B(row,c) = pkrtz(vblur p^2+t^2, vblur p*t) u32 at dword row*SROW + BOFFD + c
    // 32*148*4 = 18944 B -> 19456 alloc -> 8 blocks/CU (round-1/2 measured Occupancy ~58-63).
    __shared__ __align__(16) float plane[TH * SROW];
    __shared__ float red[4];

    const int tid = threadIdx.x;
    const int tile = blockIdx.x;             // 16x16 tiles of 32x32
    const int plane_id = blockIdx.y;         // 48 planes
    const int tile_x = tile & 15;
    const int tile_y = tile >> 4;
    const int tx = tile_x * TW;
    const int ty = tile_y * TH;
    const float* pbase = pred + (size_t)plane_id * (IMG * IMG);
    const float* tbase = tgt + (size_t)plane_id * (IMG * IMG);

    // ---- Phase 1: vertical 11-tap blur straight from global, row-pair per task ----
    if (tid < NG * 16) {
        const int g4 = tid % NG;             // col group
        const int rp = tid / NG;             // row pair
        const int r0 = rp * 2;               // local output row
        const int col = tx - 8 + (g4 << 2);  // global col of float4 (16B-aligned)
        const int ybase = ty + r0 - 5;

        f2 A0[4][2], A1[4][2];
#pragma unroll
        for (int q = 0; q < 4; ++q)
#pragma unroll
            for (int h = 0; h < 2; ++h) { A0[q][h] = (f2)0.f; A1[q][h] = (f2)0.f; }

        // Block-uniform branch (scalar, no divergence); loads plain, compiler-scheduled.
        if ((unsigned)(tile_x - 1) < 14u && (unsigned)(tile_y - 1) < 14u) {
            const float* pp = pbase + (ybase * IMG + col);
            const float* tp = tbase + (ybase * IMG + col);
#pragma unroll
            for (int k = 0; k < 12; ++k) {
                const float4 P = *(const float4*)(pp + k * IMG);
                const float4 T = *(const float4*)(tp + k * IMG);
                vtaps(P, T, k, A0, A1);
            }
        } else {
            const bool xin = (unsigned)col < (unsigned)IMG;  // all-in or all-out
#pragma unroll
            for (int k = 0; k < 12; ++k) {
                const int y = ybase + k;
                float4 P = make_float4(0.f, 0.f, 0.f, 0.f);
                float4 T = make_float4(0.f, 0.f, 0.f, 0.f);
                if (xin && (unsigned)y < (unsigned)IMG) {
                    const int gidx = y * IMG + col;
                    P = *(const float4*)(pbase + gidx);
                    T = *(const float4*)(tbase + gidx);
                }
                vtaps(P, T, k, A0, A1);
            }
        }

        // Transpose in registers -> b128 stores. r is a compile-time unroll var (see pin).
        const int cb = g4 << 2;              // pixel col base (col 0 == global tx-8)
#pragma unroll
        for (int r = 0; r < 2; ++r) {
            f2 (*A)[2] = r ? A1 : A0;
            float* rowA = &plane[(r0 + r) * SROW + (cb << 1)];
            *(float4*)rowA       = make_float4(A[0][0].x, A[1][0].x, A[0][0].y, A[1][0].y);
            *(float4*)(rowA + 4) = make_float4(A[0][1].x, A[1][1].x, A[0][1].y, A[1][1].y);
            // B: 4 pixels packed half2(ss,pt) = one uint4 = one ds_write_b128.
            uint4 bv;
            bv.x = pkh(A[2][0].x, A[3][0].x);
            bv.y = pkh(A[2][0].y, A[3][0].y);
            bv.z = pkh(A[2][1].x, A[3][1].x);
            bv.w = pkh(A[2][1].y, A[3][1].y);
            *(uint4*)&plane[(r0 + r) * SROW + BOFFD + cb] = bv;
        }
    }
    __syncthreads();

    // ---- Phase 2: packed horizontal 11-tap blur + SSIM map, 4 outputs per thread ----
    // SCATTER form: each loaded pixel is consumed immediately into the <=4 outputs it
    // feeds. Peak live ~24 dwords (acc 8 + sacc 8 + one load), vs gather's 64+.
    float lsum = 0.f;
    {
        const int oy = tid >> 3;             // 32 rows
        const int ox = (tid & 7) << 2;       // 8 groups of 4 output cols
        const float* rowbase = &plane[oy * SROW];

        f2 acc[4];                           // (mu1, mu2) per j
        f2 sacc[4];                          // (bss, bpt) per j
#pragma unroll
        for (int j = 0; j < 4; ++j) { acc[j] = (f2)0.f; sacc[j] = (f2)0.f; }

        // A part: load f2 cols ox+2..ox+17 (8 x b128, 16B-aligned). Pixel index i
        // (col ox+2+i) feeds output j with weight Gw2[i-1-j] when 0<=i-1-j<=10.
        {
            const float4* rowA = (const float4*)(rowbase + ((ox + 2) << 1));
#pragma unroll
            for (int i4 = 0; i4 < 8; ++i4) {
                const float4 q = rowA[i4];
                const f2 v[2] = {{q.x, q.y}, {q.z, q.w}};
#pragma unroll
                for (int h = 0; h < 2; ++h) {
                    const int i = 2 * i4 + h;
#pragma unroll
                    for (int j = 0; j < 4; ++j) {
                        const int k = i - 1 - j;
                        if (k >= 0 && k <= 10) acc[j] += Gw2[k] * v[h];
                    }
                }
            }
        }

        // B part: load packed pixels ox..ox+19 (5 x b128, contiguous span). Pixel
        // offset m (col ox+m) feeds output j with weight Gw2[m-3-j] when 0<=m-3-j<=10.
        {
            const uint4* rowB = (const uint4*)(rowbase + BOFFD + ox);
#pragma unroll
            for (int i4 = 0; i4 < 5; ++i4) {
                const uint4 q = rowB[i4];
                const unsigned qq[4] = {q.x, q.y, q.z, q.w};
#pragma unroll
                for (int c = 0; c < 4; ++c) {
                    const int m = 4 * i4 + c;
                    if (m >= 3 && m <= 16) {
                        const f2 v = uph(qq[c]);
#pragma unroll
                        for (int j = 0; j < 4; ++j) {
                            const int k = m - 3 - j;
                            if (k >= 0 && k <= 10) sacc[j] += Gw2[k] * v;
                        }
                    }
                }
            }
        }

        const float C1 = 0.0001f;            // 0.01^2
        const float C2 = 0.0009f;            // 0.03^2
#pragma unroll
        for (int j = 0; j < 4; ++j) {
            const float m1 = acc[j].x, m2 = acc[j].y;
            const float bss = sacc[j].x, bpt = sacc[j].y;
            const float mu1s = m1 * m1;
            const float mu2s = m2 * m2;
            const float mu12 = m1 * m2;
            const float A = mu1s + mu2s;
            const float s12 = bpt - mu12;    // sigma12
            const float sden = bss - A;      // sigma1^2 + sigma2^2
            const float num = fmaf(2.f, mu12, C1) * fmaf(2.f, s12, C2);
            const float den = (A + C1) * (sden + C2);
            lsum += num * __builtin_amdgcn_rcpf(den);   // rcp err ~1e-7 << 1.98e-2 threshold
        }
    }

    // ---- Reduction: wave shuffle -> LDS -> one plain store per block ----
#pragma unroll
    for (int off = 32; off > 0; off >>= 1) lsum += __shfl_down(lsum, off, 64);
    if ((tid & 63) == 0) red[tid >> 6] = lsum;
    __syncthreads();
    if (tid == 0) {
        const float bs = (red[0] + red[1]) + (red[2] + red[3]);
        const int bid = blockIdx.y * gridDim.x + blockIdx.x;
        if (parts_mode) {
            ws[bid] = bs;                    // contention-free
        } else {
            atomicAdd(&ws[bid & (NSLOT - 1)], bs);  // fallback: shallow contention
        }
    }
}

// Sum `count4` float4 partials from ws, write 1 - sum/N.
__global__ __launch_bounds__(1024) void ssim_final(const float4* __restrict__ ws4,
                                                   float* __restrict__ out, int count4) {
    __shared__ float red[16];
    const int tid = threadIdx.x;
    float s = 0.f;
    for (int i = tid; i < count4; i += 1024) {
        const float4 w = ws4[i];
        s += (w.x + w.y) + (w.z + w.w);
    }
#pragma unroll
    for (int off = 32; off > 0; off >>= 1) s += __shfl_down(s, off, 64);
    if ((tid & 63) == 0) red[tid >> 6] = s;
    __syncthreads();
    if (tid == 0) {
        float tot = 0.f;
#pragma unroll
        for (int i = 0; i < 16; ++i) tot += red[i];
        out[0] = 1.0f - tot * (1.0f / (float)N_TOT);
    }
}

extern "C" void kernel_launch(void* const* d_in, const int* in_sizes, int n_in,
                              void* d_out, int out_size, void* d_ws, size_t ws_size,
                              hipStream_t stream) {
    const float* pred = (const float*)d_in[0];
    const float* tgt = (const float*)d_in[1];
    float* out = (float*)d_out;
    float* ws = (float*)d_ws;

    const int parts_mode = (ws_size >= (size_t)NBLK * sizeof(float)) ? 1 : 0;
    if (!parts_mode) {
        hipMemsetAsync(ws, 0, NSLOT * sizeof(float), stream);
    }
    dim3 grid(256, 48);  // 16x16 tiles x (16*3) planes
    ssim_main<<<grid, 256, 0, stream>>>(pred, tgt, ws, parts_mode);
    ssim_final<<<1, 1024, 0, stream>>>((const float4*)ws, out,
                                       (parts_mode ? NBLK : NSLOT) / 4);
}